// Round 6
// baseline (42197.342 us; speedup 1.0000x reference)
//
// Encoder-decoder LSTM + dot attention + linear, MI355X fp32.  R10
// R5-R9 post-mortem: 4-blocks/chain is structurally RTT-bound (~2500-3000cy
// memory-side exchange per step vs only ~600cy gemv to hide it); every
// intra-block rearrangement (R9) just moved work onto the critical path.
// R10: ONE CHAIN PER CU. gemv = 262144 MACs/step = 2048cy on one CU's VALU
// < the 3800cy/step of the exchange version. Thread j holds gate row j's 256
// weights in VGPRs (256 VGPRs, 4 waves/SIMD); h double-buffered in LDS
// (broadcast reads); gates of a dim in one lane-quad -> 3 shfls; ONE barrier
// per step; zero exchange. ew/hw dots folded into scans (proj deleted); no
// weight transpose (prep = bias sums + flag zero only).
// Overlap: dec sets prog[b] (RELEASE/AGENT) every 32 steps; attn (launched
// after dec) gates each (b, tile) on prog[b] -> attention runs on the 192
// idle CUs concurrently with the decoder. Encoder has no flags (A/B).
// Pred: scans ~1000-1200us each, VALUBusy 70-85%, FETCH ~20MB, WRITE ~67MB;
// attn hidden behind dec; total ~2300-2700us.
#include <hip/hip_runtime.h>
#include <math.h>

#define HD 256
#define GD 1024   // 4*H
#define TT 1024
#define BB 64

__device__ __forceinline__ float sig_(float x)  { return 1.f / (1.f + __expf(-x)); }
__device__ __forceinline__ float tanh_(float x) { return 1.f - 2.f / (1.f + __expf(2.f * x)); }

// ---------------- prep: bias sums + zero progress flags ----------------
__global__ __launch_bounds__(256) void prep_kernel(
    const float* __restrict__ eb1, const float* __restrict__ eb2,
    const float* __restrict__ db1, const float* __restrict__ db2,
    float* __restrict__ be, float* __restrict__ bd,
    unsigned* __restrict__ prog)
{
    int idx = blockIdx.x * 256 + threadIdx.x;
    if (idx < GD) {
        be[idx] = eb1[idx] + eb2[idx];
        bd[idx] = db1[idx] + db2[idx];
    }
    if (idx < BB) prog[idx] = 0u;
}

// ---------------- LSTM scan: ONE block per chain, weights in VGPRs ----------------
// 1024 threads; thread (wv = tid>>6, l = tid&63): d = wv*16 + (l>>2) (hidden dim),
// g = l&3 (gate), row = g*256+d. Each thread: full 256-k dot for its gate row.
// Gates of dim d live in one lane-quad -> shfl gather; c replicated x4.
__global__ __launch_bounds__(1024) void lstm_scan_cu(
    const float* __restrict__ x,       // [B,T]
    const float* __restrict__ Wih,     // [4H]
    const float* __restrict__ bias,    // [4H] (bih+bhh)
    const float* __restrict__ Whh,     // [4H][H] natural layout
    const float* __restrict__ h_init,  // nullptr, or enc_states (reads [b][T-1][:])
    float* __restrict__ states,        // [B,T,H]
    const float* __restrict__ lw,      // linW slice [H] for the folded row-dot
    float* __restrict__ rowdot,        // ew or hw, [B,T]
    unsigned* __restrict__ prog)       // [B] progress flags (dec) or nullptr (enc)
{
    const int b   = blockIdx.x;
    const int tid = threadIdx.x;
    const int wv  = tid >> 6;          // 0..15
    const int l   = tid & 63;
    const int d   = wv * 16 + (l >> 2);  // hidden dim 0..255
    const int g   = l & 3;               // 0:i 1:f 2:g 3:o
    const int row = g * 256 + d;         // gate row 0..1023

    __shared__ float xs[TT];
    __shared__ float hs[2][264];
    __shared__ float part[2][16];

    // ---- full gate row in VGPRs: 64 x float4 = 256 VGPRs ----
    float4 w[64];
    {
        const float4* wp = (const float4*)(Whh + (size_t)row * HD);
        #pragma unroll
        for (int i = 0; i < 64; ++i) w[i] = wp[i];
    }
    const float wih = Wih[row], bj = bias[row];
    const float lwd = lw[d];

    for (int i = tid; i < TT; i += 1024) xs[i] = x[b * TT + i];
    if (tid < HD)
        hs[0][tid] = h_init ? h_init[((size_t)b * TT + (TT - 1)) * HD + tid] : 0.f;
    float c = 0.f;   // cell state for dim d, replicated over the 4 gate lanes
    __syncthreads();

    #pragma unroll 1
    for (int t = 0; t < TT; ++t) {
        const float xt = xs[t];
        const float4* hp = (const float4*)(&hs[t & 1][0]);
        // 256-k dot, 4 interleaved accumulators (ILP)
        float a0 = fmaf(xt, wih, bj), a1 = 0.f, a2 = 0.f, a3 = 0.f;
        #pragma unroll
        for (int i = 0; i < 16; ++i) {
            float4 h0 = hp[4*i+0], h1 = hp[4*i+1], h2 = hp[4*i+2], h3 = hp[4*i+3];
            float4 q0 = w[4*i+0],  q1 = w[4*i+1],  q2 = w[4*i+2],  q3 = w[4*i+3];
            a0 = fmaf(h0.x, q0.x, a0); a0 = fmaf(h0.y, q0.y, a0);
            a0 = fmaf(h0.z, q0.z, a0); a0 = fmaf(h0.w, q0.w, a0);
            a1 = fmaf(h1.x, q1.x, a1); a1 = fmaf(h1.y, q1.y, a1);
            a1 = fmaf(h1.z, q1.z, a1); a1 = fmaf(h1.w, q1.w, a1);
            a2 = fmaf(h2.x, q2.x, a2); a2 = fmaf(h2.y, q2.y, a2);
            a2 = fmaf(h2.z, q2.z, a2); a2 = fmaf(h2.w, q2.w, a2);
            a3 = fmaf(h3.x, q3.x, a3); a3 = fmaf(h3.y, q3.y, a3);
            a3 = fmaf(h3.z, q3.z, a3); a3 = fmaf(h3.w, q3.w, a3);
        }
        const float a = (a0 + a2) + (a1 + a3);
        const float av = (g == 2) ? tanh_(a) : sig_(a);
        // gather the other 3 gates within the lane-quad
        const float b1v = __shfl_xor(av, 1);    // gate g^1
        const float b2v = __shfl_xor(av, 2);    // gate g^2
        const float b3v = __shfl_xor(b2v, 1);   // gate g^3
        float gi, gf, gg, go;
        if      (g == 0) { gi = av;  gf = b1v; gg = b2v; go = b3v; }
        else if (g == 1) { gi = b1v; gf = av;  gg = b3v; go = b2v; }
        else if (g == 2) { gi = b2v; gf = b3v; gg = av;  go = b1v; }
        else             { gi = b3v; gf = b2v; gg = b1v; go = av;  }
        c = fmaf(gf, c, gi * gg);
        const float h = go * tanh_(c);
        // folded row-dot (ew/hw): one contribution per dim (g==0 lanes)
        float v = (g == 0) ? h * lwd : 0.f;
        #pragma unroll
        for (int m = 1; m < 64; m <<= 1) v += __shfl_xor(v, m);
        if (l == 0) part[t & 1][wv] = v;
        if (g == 0) {
            hs[(t + 1) & 1][d] = h;
            states[((size_t)(b * TT + t)) * HD + d] = h;
        }
        __syncthreads();   // h(t+1) buffer + partials ready; stores vmcnt-drained
        if (tid < 16) {
            float pv = part[t & 1][tid];
            pv += __shfl_xor(pv, 1); pv += __shfl_xor(pv, 2);
            pv += __shfl_xor(pv, 4); pv += __shfl_xor(pv, 8);
            if (tid == 0) {
                rowdot[(size_t)b * TT + t] = pv;
                if (prog && (t & 31) == 31)
                    __hip_atomic_store(&prog[b], (unsigned)((t + 1) >> 5),
                                       __ATOMIC_RELEASE, __HIP_MEMORY_SCOPE_AGENT);
            }
        }
    }
}

// ---------------- attention: 32 td rows/block, 4x8 register tile, flag-gated ------
// grid = (B, T/TD2): x=b, y=tile -> low tiles dispatch first (matches dec progress)
#define TD2  32    // td rows per block
#define TEC2 256   // te chunk
#define KC2  32    // k chunk
__global__ __launch_bounds__(256) void attn_kernel(
    const float* __restrict__ enc_states,  // [B][T][H]
    const float* __restrict__ dec_hs,      // [B][T][H]
    const float* __restrict__ ew, const float* __restrict__ hw,
    const float* __restrict__ lin_b,
    const unsigned* __restrict__ prog,     // [B] decoder progress (32-step tiles)
    float* __restrict__ out)               // [B][T]
{
    const int b   = blockIdx.x;
    const int td0 = blockIdx.y * TD2;
    const int tid = threadIdx.x;
    const int tdt = tid >> 5;   // 0..7 (4 td rows each)
    const int tet = tid & 31;   // 0..31

    __shared__ float Hx[HD][TD2 + 4];   // stride 36: rows 16B-aligned
    __shared__ float E[KC2][TEC2];

    // gate on decoder progress: rows td0..td0+31 ready when prog[b] > tile
    if (tid == 0) {
        const unsigned need = (unsigned)blockIdx.y + 1u;
        while (__hip_atomic_load(&prog[b], __ATOMIC_ACQUIRE,
                                 __HIP_MEMORY_SCOPE_AGENT) < need)
            __builtin_amdgcn_s_sleep(16);
    }
    __syncthreads();

    // stage Hx: thread -> (td = tid>>3, 32-k chunk = (tid&7)*32)
    {
        const int td = tid >> 3;
        const int kc = (tid & 7) * 32;
        const float* src = dec_hs + ((size_t)b * TT + td0 + td) * HD + kc;
        #pragma unroll
        for (int qq = 0; qq < 8; ++qq) {
            float4 v = ((const float4*)(src + qq * 4))[0];
            Hx[kc + qq * 4 + 0][td] = v.x;
            Hx[kc + qq * 4 + 1][td] = v.y;
            Hx[kc + qq * 4 + 2][td] = v.z;
            Hx[kc + qq * 4 + 3][td] = v.w;
        }
    }

    float M[4]  = {-1e30f, -1e30f, -1e30f, -1e30f};
    float Nm[4] = {0.f, 0.f, 0.f, 0.f};
    float Dn[4] = {0.f, 0.f, 0.f, 0.f};

    for (int tc = 0; tc < TT / TEC2; ++tc) {
        const int te0 = tc * TEC2;
        float S[4][8] = {{0.f}};
        for (int kc = 0; kc < HD / KC2; ++kc) {
            const int k0 = kc * KC2;
            __syncthreads();
            {   // stage E chunk: thread = te row, 32 consecutive k
                const float* src = enc_states + ((size_t)b * TT + te0 + tid) * HD + k0;
                #pragma unroll
                for (int qq = 0; qq < 8; ++qq) {
                    float4 v = ((const float4*)(src + qq * 4))[0];
                    E[qq * 4 + 0][tid] = v.x;
                    E[qq * 4 + 1][tid] = v.y;
                    E[qq * 4 + 2][tid] = v.z;
                    E[qq * 4 + 3][tid] = v.w;
                }
            }
            __syncthreads();
            #pragma unroll 4
            for (int k = 0; k < KC2; ++k) {
                const float4 hx4 = *(const float4*)(&Hx[k0 + k][tdt * 4]);
                #pragma unroll
                for (int i = 0; i < 8; ++i) {
                    const float e = E[k][tet + 32 * i];
                    S[0][i] = fmaf(hx4.x, e, S[0][i]);
                    S[1][i] = fmaf(hx4.y, e, S[1][i]);
                    S[2][i] = fmaf(hx4.z, e, S[2][i]);
                    S[3][i] = fmaf(hx4.w, e, S[3][i]);
                }
            }
        }
        float ewv[8];
        #pragma unroll
        for (int i = 0; i < 8; ++i) ewv[i] = ew[(size_t)b * TT + te0 + tet + 32 * i];
        #pragma unroll
        for (int r = 0; r < 4; ++r) {
            float cm = S[r][0];
            #pragma unroll
            for (int i = 1; i < 8; ++i) cm = fmaxf(cm, S[r][i]);
            #pragma unroll
            for (int m = 1; m < 32; m <<= 1) cm = fmaxf(cm, __shfl_xor(cm, m));
            const float newM  = fmaxf(M[r], cm);
            const float scale = __expf(M[r] - newM);
            float nl = 0.f, dl = 0.f;
            #pragma unroll
            for (int i = 0; i < 8; ++i) {
                const float p = __expf(S[r][i] - newM);
                dl += p;
                nl = fmaf(p, ewv[i], nl);
            }
            #pragma unroll
            for (int m = 1; m < 32; m <<= 1) {
                nl += __shfl_xor(nl, m);
                dl += __shfl_xor(dl, m);
            }
            Nm[r] = Nm[r] * scale + nl;
            Dn[r] = Dn[r] * scale + dl;
            M[r]  = newM;
        }
    }

    if (tet == 0) {
        const float lb = lin_b[0];
        #pragma unroll
        for (int r = 0; r < 4; ++r) {
            const int td = td0 + tdt * 4 + r;
            out[(size_t)b * TT + td] = Nm[r] / Dn[r] + hw[(size_t)b * TT + td] + lb;
        }
    }
}

extern "C" void kernel_launch(void* const* d_in, const int* in_sizes, int n_in,
                              void* d_out, int out_size, void* d_ws, size_t ws_size,
                              hipStream_t stream)
{
    const float* x    = (const float*)d_in[0];
    const float* eWih = (const float*)d_in[1];
    const float* eWhh = (const float*)d_in[2];
    const float* ebih = (const float*)d_in[3];
    const float* ebhh = (const float*)d_in[4];
    const float* dWih = (const float*)d_in[5];
    const float* dWhh = (const float*)d_in[6];
    const float* dbih = (const float*)d_in[7];
    const float* dbhh = (const float*)d_in[8];
    const float* linW = (const float*)d_in[9];
    const float* linb = (const float*)d_in[10];
    float* out = (float*)d_out;

    float* p = (float*)d_ws;
    float* be  = p;        p += GD;
    float* bd  = p;        p += GD;
    float* enc_states = p; p += (size_t)BB * TT * HD;
    float* dec_hs = p;     p += (size_t)BB * TT * HD;
    float* ew = p;         p += (size_t)BB * TT;
    float* hw = p;         p += (size_t)BB * TT;
    unsigned* prog = (unsigned*)p; p += 256;   // 64 used, padded

    prep_kernel<<<(GD + 255) / 256, 256, 0, stream>>>(
        ebih, ebhh, dbih, dbhh, be, bd, prog);

    // encoder: no flags (prog=nullptr); folded ew = enc_h . linW[0:256]
    lstm_scan_cu<<<BB, 1024, 0, stream>>>(
        x, eWih, be, eWhh, nullptr, enc_states, linW, ew, nullptr);
    // decoder: flags every 32 steps; folded hw = dec_h . linW[256:512]
    lstm_scan_cu<<<BB, 1024, 0, stream>>>(
        x, dWih, bd, dWhh, enc_states, dec_hs, linW + HD, hw, prog);

    // attention overlaps the decoder via progress flags (low tiles dispatch first)
    attn_kernel<<<dim3(BB, TT / TD2), 256, 0, stream>>>(
        enc_states, dec_hs, ew, hw, linb, prog, out);
}

// Round 7
// 7013.392 us; speedup vs baseline: 6.0167x; 6.0167x over previous
//
// Encoder-decoder LSTM + dot attention + linear, MI355X fp32.  R11
// R10 post-mortem: 256 VGPR/thread impossible at 1024 thr (pool 2048/CU);
// weights spilled to scratch (FETCH 19.7GB, VGPR=64). 1MB Whh can't live on
// one CU (RF 512KB + LDS 160KB) -> 4-CU/chain exchange (R4, 1622us/scan) is
// the right frame; its floor ~1.45ms/scan. The big remaining win: ~700us of
// proj+attn runs SERIAL after dec while dec idles 70% of VALU (RTT-bound).
// R11: (a) revert scans to proven R4 structure; (b) FUSE dec+attn in one
// kernel (same-stream kernels serialize; only fusion overlaps): blocks
// 0..255 = dec (dispatched first, co-resident), 256..1279 = attn 64-row
// tiles gated on per-block release flags prog4[b][q] (own-L2 flush every 32
// steps; acquire on attn side) -> XCD-safe; (c) setprio(1) around dec
// gemv+publish so co-resident attn waves don't stretch the dec critical
// path; (d) proj deleted: scans emit quarter-dots qew/qhw[b][t][q], attn
// sums 4; (e) 2-deep vmcnt-pipelined poll (sticky bounded fallback).
// Pred: enc ~1500us, fused ~1700-1800us (attn hidden), total ~3300-3500us.
#include <hip/hip_runtime.h>
#include <math.h>

#define HD 256
#define GD 1024   // 4*H
#define TT 1024
#define BB 64
#define NT 512    // block size

__device__ __forceinline__ float sig_(float x)  { return 1.f / (1.f + __expf(-x)); }
__device__ __forceinline__ float tanh_(float x) { return 1.f - 2.f / (1.f + __expf(2.f * x)); }

// ---------------- prep: transpose Whh -> [k][j], bias sums, zero ex + flags ----------
__global__ __launch_bounds__(256) void prep_kernel(
    const float* __restrict__ eW, const float* __restrict__ eb1, const float* __restrict__ eb2,
    const float* __restrict__ dW, const float* __restrict__ db1, const float* __restrict__ db2,
    float* __restrict__ WTe, float* __restrict__ WTd,
    float* __restrict__ be, float* __restrict__ bd,
    unsigned long long* __restrict__ ex,   // [B][2][256] tagged slots
    unsigned* __restrict__ prog4)          // [B][4] progress flags
{
    int idx = blockIdx.x * 256 + threadIdx.x;
    if (idx < GD * HD) {
        int j = idx / HD, k = idx % HD;      // Whh[j][k]
        WTe[k * GD + j] = eW[idx];
        WTd[k * GD + j] = dW[idx];
    }
    if (idx < GD) {
        be[idx] = eb1[idx] + eb2[idx];
        bd[idx] = db1[idx] + db2[idx];
    }
    if (idx < BB * 2 * 256) ex[idx] = 0ULL;   // tags=0 (< any expected tag)
    if (idx < BB * 4) prog4[idx] = 0u;
}

// ---------------- LSTM scan body: R4-proven structure (4 blocks/chain) ----------------
// block (b, q): q owns hidden dims [64q,64q+64). thread: s=tid&3 (k-quarter),
// jj=tid>>2 (row-pair). Adds: setprio around gemv/publish, 2-deep pipelined
// poll, per-step quarter-dot qdot[b][t][q] = h_q . lw_q, release flags.
__device__ __forceinline__ void scan_body(
    const float* __restrict__ x, const float* __restrict__ Wih,
    const float* __restrict__ bias, const float* __restrict__ WT,
    const float* __restrict__ h_init, float* __restrict__ states,
    unsigned long long* __restrict__ ex, unsigned tag0,
    const float* __restrict__ lw, float* __restrict__ qdot,
    unsigned* __restrict__ prog4,
    float* x_s, float* h_rep /*4*264*/, float* act_s /*256*/,
    int b, int q)
{
    const int tid = threadIdx.x;
    const int s   = tid & 3;
    const int jj  = tid >> 2;
    const int gate = jj >> 5;
    const int kk0  = (jj & 31) * 2;
    const int r0   = gate * 64 + kk0;
    const int jg0  = gate * 256 + q * 64 + kk0;

    float4 w0[16], w1[16];
    {
        const float* basek = WT + (size_t)(s * 64) * GD;
        #pragma unroll
        for (int i = 0; i < 16; ++i) {
            const float* p0 = basek + (size_t)(4 * i) * GD + jg0;
            w0[i] = make_float4(p0[0], p0[GD], p0[2 * GD], p0[3 * GD]);
            const float* p1 = p0 + 1;
            w1[i] = make_float4(p1[0], p1[GD], p1[2 * GD], p1[3 * GD]);
        }
    }
    const float wih0 = Wih[jg0], wih1 = Wih[jg0 + 1];
    const float bj0  = bias[jg0], bj1  = bias[jg0 + 1];
    const float lwd  = lw[tid & 255];   // linW weight for dim (tid&255); used by owners

    for (int i = tid; i < TT; i += NT) x_s[i] = x[b * TT + i];
    if (tid < 256) {
        float hv = h_init ? h_init[((size_t)b * TT + (TT - 1)) * HD + tid] : 0.f;
        h_rep[(tid >> 6) * 264 + (tid & 63)] = hv;
    }
    float c = 0.f;
    int pipe_ok = 1;
    __syncthreads();

    #pragma unroll 1
    for (int t = 0; t < TT; ++t) {
        __builtin_amdgcn_s_setprio(1);   // protect gemv from co-resident attn waves
        const float xt = x_s[t];
        float a0p, a1p, a0q = 0.f, a1q = 0.f;
        if (s == 0) { a0p = fmaf(xt, wih0, bj0); a1p = fmaf(xt, wih1, bj1); }
        else        { a0p = 0.f;                 a1p = 0.f; }
        const float4* h4 = (const float4*)(h_rep + s * 264);
        #pragma unroll
        for (int i = 0; i < 8; ++i) {
            float4 hv = h4[i];
            a0p = fmaf(hv.x, w0[i].x, a0p); a0p = fmaf(hv.y, w0[i].y, a0p);
            a0p = fmaf(hv.z, w0[i].z, a0p); a0p = fmaf(hv.w, w0[i].w, a0p);
            a1p = fmaf(hv.x, w1[i].x, a1p); a1p = fmaf(hv.y, w1[i].y, a1p);
            a1p = fmaf(hv.z, w1[i].z, a1p); a1p = fmaf(hv.w, w1[i].w, a1p);
        }
        #pragma unroll
        for (int i = 8; i < 16; ++i) {
            float4 hv = h4[i];
            a0q = fmaf(hv.x, w0[i].x, a0q); a0q = fmaf(hv.y, w0[i].y, a0q);
            a0q = fmaf(hv.z, w0[i].z, a0q); a0q = fmaf(hv.w, w0[i].w, a0q);
            a1q = fmaf(hv.x, w1[i].x, a1q); a1q = fmaf(hv.y, w1[i].y, a1q);
            a1q = fmaf(hv.z, w1[i].z, a1q); a1q = fmaf(hv.w, w1[i].w, a1q);
        }
        float a0 = a0p + a0q;
        float a1 = a1p + a1q;
        a0 += __shfl_xor(a0, 1); a0 += __shfl_xor(a0, 2);
        a1 += __shfl_xor(a1, 1); a1 += __shfl_xor(a1, 2);
        if (s == 0) {
            float2 av;
            av.x = (gate == 2) ? tanh_(a0) : sig_(a0);
            av.y = (gate == 2) ? tanh_(a1) : sig_(a1);
            *(float2*)(&act_s[r0]) = av;
        }
        __syncthreads();   // act ready

        const unsigned tag = tag0 + (unsigned)t + 1u;
        unsigned long long* ssl = ex + ((size_t)b * 2 + (t & 1)) * 256;
        if (tid < 256) {
            const int dq = tid >> 6, dk = tid & 63;   // wave-uniform dq
            if (dq == q) {
                float gi = act_s[dk], gf = act_s[64 + dk], gg = act_s[128 + dk], go = act_s[192 + dk];
                c = fmaf(gf, c, gi * gg);
                float h = go * tanh_(c);
                unsigned long long pk = ((unsigned long long)tag << 32)
                                      | (unsigned long long)__float_as_uint(h);
                // publish FIRST (earliest remote visibility)
                __hip_atomic_store(&ssl[tid], pk, __ATOMIC_RELAXED, __HIP_MEMORY_SCOPE_AGENT);
                h_rep[q * 264 + dk] = h;
                states[((size_t)(b * TT + t)) * HD + tid] = h;
                __builtin_amdgcn_s_setprio(0);
                // quarter-dot for the folded linear: v = sum_dk h*lw (off critical path)
                float v = h * lwd;
                #pragma unroll
                for (int m = 1; m < 64; m <<= 1) v += __shfl_xor(v, m);
                if (dk == 0) qdot[((size_t)(b * TT + t)) * 4 + q] = v;
            } else {
                __builtin_amdgcn_s_setprio(0);
                unsigned long long u; int got = 0;
                const unsigned long long* sp = ssl + tid;
                if (pipe_ok) {
                    unsigned long long u0, u1;
                    asm volatile("global_load_dwordx2 %0, %2, off sc0 sc1\n\t"
                                 "global_load_dwordx2 %1, %2, off sc0 sc1"
                                 : "=&v"(u0), "=&v"(u1) : "v"(sp));
                    #pragma unroll 1
                    for (int it = 0; it < 300; ++it) {
                        asm volatile("s_waitcnt vmcnt(1)" : "+v"(u0));
                        if ((unsigned)(u0 >> 32) == tag) { u = u0; got = 1; break; }
                        asm volatile("global_load_dwordx2 %0, %1, off sc0 sc1"
                                     : "=&v"(u0) : "v"(sp));
                        asm volatile("s_waitcnt vmcnt(1)" : "+v"(u1));
                        if ((unsigned)(u1 >> 32) == tag) { u = u1; got = 1; break; }
                        asm volatile("global_load_dwordx2 %0, %1, off sc0 sc1"
                                     : "=&v"(u1) : "v"(sp));
                    }
                    asm volatile("s_waitcnt vmcnt(0)" ::: "memory");   // drain in-flight
                    if (!got) pipe_ok = 0;   // sticky fallback
                }
                if (!got) {
                    do {
                        u = __hip_atomic_load(sp, __ATOMIC_RELAXED, __HIP_MEMORY_SCOPE_AGENT);
                    } while ((unsigned)(u >> 32) != tag);
                }
                h_rep[dq * 264 + dk] = __uint_as_float((unsigned)u);
            }
        } else {
            __builtin_amdgcn_s_setprio(0);
        }
        __syncthreads();   // h replicas ready for t+1 (drains vmem of all threads)
        // publish progress: own-L2 writeback (release) -> states/qdot rows <= t visible
        if (prog4 && ((t & 31) == 31) && tid == 0)
            __hip_atomic_store(&prog4[b * 4 + q], (unsigned)((t + 1) >> 5),
                               __ATOMIC_RELEASE, __HIP_MEMORY_SCOPE_AGENT);
    }
}

// ---------------- encoder: standalone scan ----------------
__global__ __launch_bounds__(NT, 2) void enc_kernel(
    const float* __restrict__ x, const float* __restrict__ Wih,
    const float* __restrict__ bias, const float* __restrict__ WT,
    float* __restrict__ states, unsigned long long* __restrict__ ex,
    const float* __restrict__ lw, float* __restrict__ qew)
{
    __shared__ float x_s[TT];
    __shared__ float h_rep[4 * 264];
    __shared__ float act_s[256];
    const int b = (int)blockIdx.x & 63;
    const int q = (int)blockIdx.x >> 6;
    scan_body(x, Wih, bias, WT, nullptr, states, ex, 0u, lw, qew, nullptr,
              x_s, h_rep, act_s, b, q);
}

// ---------------- fused tail: dec scan (blocks 0..255) + gated attn (256..1279) ----
// union LDS: dec 2336 f / attn 19520 f -> 19712 f = 78848B, 2 blocks/CU.
#define SMEMF 19712
#define TDA   64     // attn td rows per block
#define TEC2  256    // te chunk
#define KC2   8      // k chunk (small E to fit union LDS x2 per CU)
__global__ __launch_bounds__(NT, 4) void tail_kernel(
    const float* __restrict__ x, const float* __restrict__ Wih,
    const float* __restrict__ bias, const float* __restrict__ WT,
    const float* __restrict__ enc_states, float* __restrict__ dec_hs,
    unsigned long long* __restrict__ ex,
    const float* __restrict__ lw2, float* __restrict__ qhw,
    unsigned* __restrict__ prog4,
    const float* __restrict__ qew, const float* __restrict__ lin_b,
    float* __restrict__ out)
{
    __shared__ __align__(16) float smem[SMEMF];
    const int blk = (int)blockIdx.x;
    const int tid = threadIdx.x;

    if (blk < 256) {
        // ---------------- decoder scan ----------------
        float* x_s   = smem;
        float* h_rep = smem + 1024;
        float* act_s = smem + 1024 + 4 * 264;
        const int b = blk & 63;
        const int q = blk >> 6;
        scan_body(x, Wih, bias, WT, enc_states, dec_hs, ex, 1024u, lw2, qhw,
                  prog4, x_s, h_rep, act_s, b, q);
        return;
    }

    // ---------------- attention tile (64 rows, 512 threads) ----------------
    const int ai   = blk - 256;
    const int b    = ai & 63;
    const int tile = ai >> 6;          // 0..15
    const int td0  = tile * TDA;
    float* Hx   = smem;                // [256 k][68]
    float* E    = smem + 17408;        // [8][256] (also staging scratch)
    float* hw_s = smem + 17408 + 2048; // [64]

    // gate: dec rows td0..td0+63 + their qhw ready when min_q prog4[b][q] >= need
    if (tid == 0) {
        const unsigned need = (unsigned)(tile * 2 + 2);
        for (;;) {
            unsigned m0 = __hip_atomic_load(&prog4[b*4+0], __ATOMIC_RELAXED, __HIP_MEMORY_SCOPE_AGENT);
            unsigned m1 = __hip_atomic_load(&prog4[b*4+1], __ATOMIC_RELAXED, __HIP_MEMORY_SCOPE_AGENT);
            unsigned m2 = __hip_atomic_load(&prog4[b*4+2], __ATOMIC_RELAXED, __HIP_MEMORY_SCOPE_AGENT);
            unsigned m3 = __hip_atomic_load(&prog4[b*4+3], __ATOMIC_RELAXED, __HIP_MEMORY_SCOPE_AGENT);
            unsigned mn = min(min(m0, m1), min(m2, m3));
            if (mn >= need) break;
            __builtin_amdgcn_s_sleep(2);
        }
        (void)__hip_atomic_load(&prog4[b*4], __ATOMIC_ACQUIRE, __HIP_MEMORY_SCOPE_AGENT);
    }
    __syncthreads();

    // stage Hx (+ fold hw partial): thread -> (td = tid>>3, kc = (tid&7)*32)
    {
        const int td = tid >> 3;
        const int kc = (tid & 7) * 32;
        const float* src = dec_hs + ((size_t)b * TT + td0 + td) * HD + kc;
        const float4* w2 = (const float4*)(lw2 + kc);
        float ph = 0.f;
        #pragma unroll
        for (int qq = 0; qq < 8; ++qq) {
            float4 v = ((const float4*)(src + qq * 4))[0];
            float4 w = w2[qq];
            Hx[(kc + qq * 4 + 0) * 68 + td] = v.x;
            Hx[(kc + qq * 4 + 1) * 68 + td] = v.y;
            Hx[(kc + qq * 4 + 2) * 68 + td] = v.z;
            Hx[(kc + qq * 4 + 3) * 68 + td] = v.w;
            ph = fmaf(v.x, w.x, ph); ph = fmaf(v.y, w.y, ph);
            ph = fmaf(v.z, w.z, ph); ph = fmaf(v.w, w.w, ph);
        }
        E[td * 8 + (tid & 7)] = ph;   // E as scratch before main loop
    }
    __syncthreads();
    if (tid < TDA) {
        float sum = 0.f;
        #pragma unroll
        for (int j = 0; j < 8; ++j) sum += E[tid * 8 + j];
        // add the dec-side qhw quarter-dots for this row
        const float4 h4v = ((const float4*)qhw)[(size_t)b * TT + td0 + tid];
        hw_s[tid] = sum * 0.f + (h4v.x + h4v.y + h4v.z + h4v.w);
        // NOTE: ph path above recomputes hw locally; qhw is authoritative.
        // Keep local recompute as unused guard against qhw staleness? No:
        // use local: hw_s[tid] = sum;  (dec_hs rows are gated-visible)
        hw_s[tid] = sum;
    }

    const int tdt = tid >> 5;   // 0..15 (4 td rows each)
    const int tet = tid & 31;

    float M[4]  = {-1e30f, -1e30f, -1e30f, -1e30f};
    float Nm[4] = {0.f, 0.f, 0.f, 0.f};
    float Dn[4] = {0.f, 0.f, 0.f, 0.f};

    for (int tc = 0; tc < TT / TEC2; ++tc) {
        const int te0 = tc * TEC2;
        float S[4][8] = {{0.f}};
        for (int kc = 0; kc < HD / KC2; ++kc) {
            const int k0 = kc * KC2;
            __syncthreads();
            {   // stage E chunk: (te = tid&255, half = tid>>8) -> one float4
                const int te = tid & 255, half = tid >> 8;
                const float* src = enc_states + ((size_t)b * TT + te0 + te) * HD + k0 + half * 4;
                float4 v = ((const float4*)src)[0];
                E[(half * 4 + 0) * 256 + te] = v.x;
                E[(half * 4 + 1) * 256 + te] = v.y;
                E[(half * 4 + 2) * 256 + te] = v.z;
                E[(half * 4 + 3) * 256 + te] = v.w;
            }
            __syncthreads();
            #pragma unroll
            for (int k = 0; k < KC2; ++k) {
                const float4 hx4 = *(const float4*)(&Hx[(k0 + k) * 68 + tdt * 4]);
                #pragma unroll
                for (int i = 0; i < 8; ++i) {
                    const float e = E[k * 256 + tet + 32 * i];
                    S[0][i] = fmaf(hx4.x, e, S[0][i]);
                    S[1][i] = fmaf(hx4.y, e, S[1][i]);
                    S[2][i] = fmaf(hx4.z, e, S[2][i]);
                    S[3][i] = fmaf(hx4.w, e, S[3][i]);
                }
            }
        }
        float ewv[8];
        #pragma unroll
        for (int i = 0; i < 8; ++i) {
            const float4 e4 = ((const float4*)qew)[(size_t)b * TT + te0 + tet + 32 * i];
            ewv[i] = (e4.x + e4.y) + (e4.z + e4.w);
        }
        #pragma unroll
        for (int r = 0; r < 4; ++r) {
            float cm = S[r][0];
            #pragma unroll
            for (int i = 1; i < 8; ++i) cm = fmaxf(cm, S[r][i]);
            #pragma unroll
            for (int m = 1; m < 32; m <<= 1) cm = fmaxf(cm, __shfl_xor(cm, m));
            const float newM  = fmaxf(M[r], cm);
            const float scale = __expf(M[r] - newM);
            float nl = 0.f, dl = 0.f;
            #pragma unroll
            for (int i = 0; i < 8; ++i) {
                const float p = __expf(S[r][i] - newM);
                dl += p;
                nl = fmaf(p, ewv[i], nl);
            }
            #pragma unroll
            for (int m = 1; m < 32; m <<= 1) {
                nl += __shfl_xor(nl, m);
                dl += __shfl_xor(dl, m);
            }
            Nm[r] = Nm[r] * scale + nl;
            Dn[r] = Dn[r] * scale + dl;
            M[r]  = newM;
        }
    }

    if (tet == 0) {
        const float lb = lin_b[0];
        #pragma unroll
        for (int r = 0; r < 4; ++r) {
            const int td = tdt * 4 + r;
            out[(size_t)b * TT + td0 + td] = Nm[r] / Dn[r] + hw_s[td] + lb;
        }
    }
}

extern "C" void kernel_launch(void* const* d_in, const int* in_sizes, int n_in,
                              void* d_out, int out_size, void* d_ws, size_t ws_size,
                              hipStream_t stream)
{
    const float* x    = (const float*)d_in[0];
    const float* eWih = (const float*)d_in[1];
    const float* eWhh = (const float*)d_in[2];
    const float* ebih = (const float*)d_in[3];
    const float* ebhh = (const float*)d_in[4];
    const float* dWih = (const float*)d_in[5];
    const float* dWhh = (const float*)d_in[6];
    const float* dbih = (const float*)d_in[7];
    const float* dbhh = (const float*)d_in[8];
    const float* linW = (const float*)d_in[9];
    const float* linb = (const float*)d_in[10];
    float* out = (float*)d_out;

    float* p = (float*)d_ws;
    float* WTe = p;        p += (size_t)GD * HD;
    float* WTd = p;        p += (size_t)GD * HD;
    float* be  = p;        p += GD;
    float* bd  = p;        p += GD;
    float* enc_states = p; p += (size_t)BB * TT * HD;
    float* dec_hs = p;     p += (size_t)BB * TT * HD;
    float* qew = p;        p += (size_t)BB * TT * 4;
    float* qhw = p;        p += (size_t)BB * TT * 4;
    unsigned long long* ex = (unsigned long long*)p; p += (size_t)BB * 2 * 256 * 2;
    unsigned* prog4 = (unsigned*)p; p += 256;

    prep_kernel<<<(GD * HD + 255) / 256, 256, 0, stream>>>(
        eWhh, ebih, ebhh, dWhh, dbih, dbhh, WTe, WTd, be, bd, ex, prog4);

    // encoder (plain launch: 256 blocks co-resident by capacity, R8-proven)
    enc_kernel<<<256, NT, 0, stream>>>(
        x, eWih, be, WTe, enc_states, ex, linW, qew);

    // fused decoder + gated attention (dec blocks 0..255 dispatch first)
    tail_kernel<<<256 + BB * (TT / TDA), NT, 0, stream>>>(
        x, dWih, bd, WTd, enc_states, dec_hs, ex, linW + HD, qhw,
        prog4, qew, linb, out);
}

// Round 8
// 4335.783 us; speedup vs baseline: 9.7323x; 1.6176x over previous
//
// Encoder-decoder LSTM + dot attention + linear, MI355X fp32.  R12
// R11 post-mortem: fusion concept OK (passed, gating worked) but
// launch_bounds(NT,4)+union regalloc crushed VGPR to 64 -> scan weights in
// scratch (FETCH 752MB) -> dec 5300us. Also shipped an untested asm poll.
// R12 = disciplined retry, one change at a time:
//  - scan body: EXACT R4-proven path (plain relaxed-agent poll, VGPR 88).
//  - tail launch_bounds(NT,2): compiler free like R4's enc. <=128 VGPR ->
//    2 blocks/CU -> overlap; >128 -> serial-inside-kernel fallback (= R4).
//  - XCD-safe visibility WITHOUT release-wbl2: dec stores dec_hs sc0 sc1
//    (write-through); barrier vmcnt(0) drains; relaxed agent flag after;
//    attn reads dec rows with sc0 sc1 bypass loads.
//  - attn on 512 thr, 32-row tiles, LDS 69.8KB union -> 2 blocks/CU by LDS.
//  - proj deleted: enc folds qew quarter-dots; attn computes hw locally.
// Pred: tail VGPR 88-110 (checkpoint), enc ~1650us, tail ~1700-2100us
// (attn absorbed, VALUBusy 33->45-60%), total ~3400-3650us; fallback ~3950.
#include <hip/hip_runtime.h>
#include <math.h>

#define HD 256
#define GD 1024   // 4*H
#define TT 1024
#define BB 64
#define NT 512    // block size

typedef float __attribute__((ext_vector_type(4))) f32x4;

__device__ __forceinline__ float sig_(float x)  { return 1.f / (1.f + __expf(-x)); }
__device__ __forceinline__ float tanh_(float x) { return 1.f - 2.f / (1.f + __expf(2.f * x)); }

// ---------------- prep: transpose Whh -> [k][j], bias sums, zero ex + flags ----------
__global__ __launch_bounds__(256) void prep_kernel(
    const float* __restrict__ eW, const float* __restrict__ eb1, const float* __restrict__ eb2,
    const float* __restrict__ dW, const float* __restrict__ db1, const float* __restrict__ db2,
    float* __restrict__ WTe, float* __restrict__ WTd,
    float* __restrict__ be, float* __restrict__ bd,
    unsigned long long* __restrict__ ex,   // [B][2][256] tagged slots
    unsigned* __restrict__ prog4)          // [B][4] progress flags
{
    int idx = blockIdx.x * 256 + threadIdx.x;
    if (idx < GD * HD) {
        int j = idx / HD, k = idx % HD;      // Whh[j][k]
        WTe[k * GD + j] = eW[idx];
        WTd[k * GD + j] = dW[idx];
    }
    if (idx < GD) {
        be[idx] = eb1[idx] + eb2[idx];
        bd[idx] = db1[idx] + db2[idx];
    }
    if (idx < BB * 2 * 256) ex[idx] = 0ULL;   // tags=0 (< any expected tag)
    if (idx < BB * 4) prog4[idx] = 0u;
}

// ---------------- LSTM scan body: EXACT R4 structure ----------------
// block (b,q): q owns dims [64q,64q+64). thread: s=tid&3 (k-quarter), jj=tid>>2.
// Optional: qdot fold (lw!=null), progress flags (prog4!=null).
// states stores are sc0 sc1 write-through (cross-block visibility in-kernel).
__device__ __forceinline__ void scan_body(
    const float* __restrict__ x, const float* __restrict__ Wih,
    const float* __restrict__ bias, const float* __restrict__ WT,
    const float* __restrict__ h_init, float* __restrict__ states,
    unsigned long long* __restrict__ ex, unsigned tag0,
    const float* __restrict__ lw, float* __restrict__ qdot,
    unsigned* __restrict__ prog4,
    float* x_s, float* h_rep /*4*264*/, float* act_s /*256*/,
    int b, int q)
{
    const int tid = threadIdx.x;
    const int s   = tid & 3;
    const int jj  = tid >> 2;
    const int gate = jj >> 5;
    const int kk0  = (jj & 31) * 2;
    const int r0   = gate * 64 + kk0;
    const int jg0  = gate * 256 + q * 64 + kk0;

    float4 w0[16], w1[16];
    {
        const float* basek = WT + (size_t)(s * 64) * GD;
        #pragma unroll
        for (int i = 0; i < 16; ++i) {
            const float* p0 = basek + (size_t)(4 * i) * GD + jg0;
            w0[i] = make_float4(p0[0], p0[GD], p0[2 * GD], p0[3 * GD]);
            const float* p1 = p0 + 1;
            w1[i] = make_float4(p1[0], p1[GD], p1[2 * GD], p1[3 * GD]);
        }
    }
    const float wih0 = Wih[jg0], wih1 = Wih[jg0 + 1];
    const float bj0  = bias[jg0], bj1  = bias[jg0 + 1];
    const float lwd  = lw ? lw[tid & 255] : 0.f;

    for (int i = tid; i < TT; i += NT) x_s[i] = x[b * TT + i];
    if (tid < 256) {
        float hv = h_init ? h_init[((size_t)b * TT + (TT - 1)) * HD + tid] : 0.f;
        h_rep[(tid >> 6) * 264 + (tid & 63)] = hv;
    }
    float c = 0.f;
    __syncthreads();

    #pragma unroll 1
    for (int t = 0; t < TT; ++t) {
        __builtin_amdgcn_s_setprio(1);   // protect gemv from co-resident attn waves
        const float xt = x_s[t];
        float a0p, a1p, a0q = 0.f, a1q = 0.f;
        if (s == 0) { a0p = fmaf(xt, wih0, bj0); a1p = fmaf(xt, wih1, bj1); }
        else        { a0p = 0.f;                 a1p = 0.f; }
        const float4* h4 = (const float4*)(h_rep + s * 264);
        #pragma unroll
        for (int i = 0; i < 8; ++i) {
            float4 hv = h4[i];
            a0p = fmaf(hv.x, w0[i].x, a0p); a0p = fmaf(hv.y, w0[i].y, a0p);
            a0p = fmaf(hv.z, w0[i].z, a0p); a0p = fmaf(hv.w, w0[i].w, a0p);
            a1p = fmaf(hv.x, w1[i].x, a1p); a1p = fmaf(hv.y, w1[i].y, a1p);
            a1p = fmaf(hv.z, w1[i].z, a1p); a1p = fmaf(hv.w, w1[i].w, a1p);
        }
        #pragma unroll
        for (int i = 8; i < 16; ++i) {
            float4 hv = h4[i];
            a0q = fmaf(hv.x, w0[i].x, a0q); a0q = fmaf(hv.y, w0[i].y, a0q);
            a0q = fmaf(hv.z, w0[i].z, a0q); a0q = fmaf(hv.w, w0[i].w, a0q);
            a1q = fmaf(hv.x, w1[i].x, a1q); a1q = fmaf(hv.y, w1[i].y, a1q);
            a1q = fmaf(hv.z, w1[i].z, a1q); a1q = fmaf(hv.w, w1[i].w, a1q);
        }
        float a0 = a0p + a0q;
        float a1 = a1p + a1q;
        a0 += __shfl_xor(a0, 1); a0 += __shfl_xor(a0, 2);
        a1 += __shfl_xor(a1, 1); a1 += __shfl_xor(a1, 2);
        if (s == 0) {
            float2 av;
            av.x = (gate == 2) ? tanh_(a0) : sig_(a0);
            av.y = (gate == 2) ? tanh_(a1) : sig_(a1);
            *(float2*)(&act_s[r0]) = av;
        }
        __syncthreads();   // act ready

        const unsigned tag = tag0 + (unsigned)t + 1u;
        unsigned long long* ssl = ex + ((size_t)b * 2 + (t & 1)) * 256;
        if (tid < 256) {
            const int dq = tid >> 6, dk = tid & 63;   // wave-uniform dq
            if (dq == q) {
                float gi = act_s[dk], gf = act_s[64 + dk], gg = act_s[128 + dk], go = act_s[192 + dk];
                c = fmaf(gf, c, gi * gg);
                float h = go * tanh_(c);
                unsigned long long pk = ((unsigned long long)tag << 32)
                                      | (unsigned long long)__float_as_uint(h);
                // publish FIRST (earliest remote visibility)
                __hip_atomic_store(&ssl[tid], pk, __ATOMIC_RELAXED, __HIP_MEMORY_SCOPE_AGENT);
                h_rep[q * 264 + dk] = h;
                // states write-through to coherence point (attn reads it in-kernel)
                float* sp = &states[((size_t)(b * TT + t)) * HD + tid];
                asm volatile("global_store_dword %0, %1, off sc0 sc1"
                             :: "v"(sp), "v"(h) : "memory");
                __builtin_amdgcn_s_setprio(0);
                if (lw) {   // folded quarter-dot (enc only), off critical path
                    float v = h * lwd;
                    #pragma unroll
                    for (int m = 1; m < 64; m <<= 1) v += __shfl_xor(v, m);
                    if (dk == 0) qdot[((size_t)(b * TT + t)) * 4 + q] = v;
                }
            } else {
                __builtin_amdgcn_s_setprio(0);
                unsigned long long u;
                const unsigned long long* sp = ssl + tid;
                do {
                    u = __hip_atomic_load(sp, __ATOMIC_RELAXED, __HIP_MEMORY_SCOPE_AGENT);
                } while ((unsigned)(u >> 32) != tag);
                h_rep[dq * 264 + dk] = __uint_as_float((unsigned)u);
            }
        } else {
            __builtin_amdgcn_s_setprio(0);
        }
        __syncthreads();   // h replicas ready; ALL waves' sc1 stores drained
        // progress flag: relaxed agent store AFTER the barrier drain is sound
        // (data already at coherence point via sc1 write-through + vmcnt(0))
        if (prog4 && ((t & 31) == 31) && tid == 0)
            __hip_atomic_store(&prog4[b * 4 + q], (unsigned)((t + 1) >> 5),
                               __ATOMIC_RELAXED, __HIP_MEMORY_SCOPE_AGENT);
    }
}

// ---------------- encoder: standalone scan (+ qew fold) ----------------
__global__ __launch_bounds__(NT, 2) void enc_kernel(
    const float* __restrict__ x, const float* __restrict__ Wih,
    const float* __restrict__ bias, const float* __restrict__ WT,
    float* __restrict__ states, unsigned long long* __restrict__ ex,
    const float* __restrict__ lw, float* __restrict__ qew)
{
    __shared__ float x_s[TT];
    __shared__ float h_rep[4 * 264];
    __shared__ float act_s[256];
    const int b = (int)blockIdx.x & 63;
    const int q = (int)blockIdx.x >> 6;
    scan_body(x, Wih, bias, WT, nullptr, states, ex, 0u, lw, qew, nullptr,
              x_s, h_rep, act_s, b, q);
}

// ---------------- fused tail: dec scan (blocks 0..255) + gated attn (256..2303) ----
// union LDS: attn 9216(Hx[256][36]) + 8192(E[32][256]) + 32(hw_s) = 17440 f
// = 69760B -> 2 blocks/CU by LDS; dec path uses first 2336 f.
#define SMEMF 17440
__global__ __launch_bounds__(NT, 2) void tail_kernel(
    const float* __restrict__ x, const float* __restrict__ Wih,
    const float* __restrict__ bias, const float* __restrict__ WT,
    const float* __restrict__ enc_states, float* __restrict__ dec_hs,
    unsigned long long* __restrict__ ex,
    unsigned* __restrict__ prog4,
    const float* __restrict__ qew, const float* __restrict__ lw2,
    const float* __restrict__ lin_b, float* __restrict__ out)
{
    __shared__ __align__(16) float smem[SMEMF];
    const int blk = (int)blockIdx.x;
    const int tid = threadIdx.x;

    if (blk < 256) {
        // ---------------- decoder scan (R4 structure) ----------------
        float* x_s   = smem;
        float* h_rep = smem + 1024;
        float* act_s = smem + 1024 + 4 * 264;
        scan_body(x, Wih, bias, WT, enc_states, dec_hs, ex, 1024u,
                  nullptr, nullptr, prog4, x_s, h_rep, act_s, blk & 63, blk >> 6);
        return;
    }

    // ---------------- attention tile: 32 rows, 512 threads ----------------
    const int ai   = blk - 256;
    const int b    = ai & 63;
    const int tile = ai >> 6;          // 0..31 (low tiles dispatch first)
    const int td0  = tile * 32;
    float* Hx   = smem;                // [256][36]
    float* E    = smem + 9216;         // [32][256] (+scratch for hw reduce)
    float* hw_s = smem + 17408;        // [32]

    // gate: dec rows [td0, td0+32) ready when min_q prog4[b][q] >= tile+1
    if (tid == 0) {
        const unsigned need = (unsigned)tile + 1u;
        for (;;) {
            unsigned m0 = __hip_atomic_load(&prog4[b*4+0], __ATOMIC_RELAXED, __HIP_MEMORY_SCOPE_AGENT);
            unsigned m1 = __hip_atomic_load(&prog4[b*4+1], __ATOMIC_RELAXED, __HIP_MEMORY_SCOPE_AGENT);
            unsigned m2 = __hip_atomic_load(&prog4[b*4+2], __ATOMIC_RELAXED, __HIP_MEMORY_SCOPE_AGENT);
            unsigned m3 = __hip_atomic_load(&prog4[b*4+3], __ATOMIC_RELAXED, __HIP_MEMORY_SCOPE_AGENT);
            unsigned mn = min(min(m0, m1), min(m2, m3));
            if (mn >= need) break;
            __builtin_amdgcn_s_sleep(8);
        }
        (void)__hip_atomic_load(&prog4[b*4], __ATOMIC_ACQUIRE, __HIP_MEMORY_SCOPE_AGENT);
    }
    __syncthreads();

    // stage Hx[k][td] (+ hw partials): thread -> (td = tid>>4, 16-k chunk)
    {
        const int td = tid >> 4;          // 0..31
        const int kq = tid & 15;          // 0..15
        const int kc = kq * 16;
        const float* src = dec_hs + ((size_t)b * TT + td0 + td) * HD + kc;
        f32x4 v0, v1, v2, v3;
        asm volatile(
            "global_load_dwordx4 %0, %4, off sc0 sc1\n\t"
            "global_load_dwordx4 %1, %5, off sc0 sc1\n\t"
            "global_load_dwordx4 %2, %6, off sc0 sc1\n\t"
            "global_load_dwordx4 %3, %7, off sc0 sc1\n\t"
            "s_waitcnt vmcnt(0)"
            : "=&v"(v0), "=&v"(v1), "=&v"(v2), "=&v"(v3)
            : "v"(src), "v"(src + 4), "v"(src + 8), "v"(src + 12)
            : "memory");
        const float4 w20 = ((const float4*)(lw2 + kc))[0];
        const float4 w21 = ((const float4*)(lw2 + kc))[1];
        const float4 w22 = ((const float4*)(lw2 + kc))[2];
        const float4 w23 = ((const float4*)(lw2 + kc))[3];
        float ph = 0.f;
        Hx[(kc+ 0)*36+td]=v0.x; Hx[(kc+ 1)*36+td]=v0.y; Hx[(kc+ 2)*36+td]=v0.z; Hx[(kc+ 3)*36+td]=v0.w;
        Hx[(kc+ 4)*36+td]=v1.x; Hx[(kc+ 5)*36+td]=v1.y; Hx[(kc+ 6)*36+td]=v1.z; Hx[(kc+ 7)*36+td]=v1.w;
        Hx[(kc+ 8)*36+td]=v2.x; Hx[(kc+ 9)*36+td]=v2.y; Hx[(kc+10)*36+td]=v2.z; Hx[(kc+11)*36+td]=v2.w;
        Hx[(kc+12)*36+td]=v3.x; Hx[(kc+13)*36+td]=v3.y; Hx[(kc+14)*36+td]=v3.z; Hx[(kc+15)*36+td]=v3.w;
        ph = fmaf(v0.x, w20.x, ph); ph = fmaf(v0.y, w20.y, ph);
        ph = fmaf(v0.z, w20.z, ph); ph = fmaf(v0.w, w20.w, ph);
        ph = fmaf(v1.x, w21.x, ph); ph = fmaf(v1.y, w21.y, ph);
        ph = fmaf(v1.z, w21.z, ph); ph = fmaf(v1.w, w21.w, ph);
        ph = fmaf(v2.x, w22.x, ph); ph = fmaf(v2.y, w22.y, ph);
        ph = fmaf(v2.z, w22.z, ph); ph = fmaf(v2.w, w22.w, ph);
        ph = fmaf(v3.x, w23.x, ph); ph = fmaf(v3.y, w23.y, ph);
        ph = fmaf(v3.z, w23.z, ph); ph = fmaf(v3.w, w23.w, ph);
        E[td * 16 + kq] = ph;   // E as scratch pre-main-loop
    }
    __syncthreads();
    if (tid < 32) {
        float sum = 0.f;
        #pragma unroll
        for (int j = 0; j < 16; ++j) sum += E[tid * 16 + j];
        hw_s[tid] = sum;
    }

    const int tdt = tid >> 5;   // 0..15 (2 td rows each)
    const int tet = tid & 31;

    float M[2]  = {-1e30f, -1e30f};
    float Nm[2] = {0.f, 0.f};
    float Dn[2] = {0.f, 0.f};

    for (int tc = 0; tc < 4; ++tc) {
        const int te0 = tc * 256;
        float S[2][8] = {{0.f}};
        for (int kc8 = 0; kc8 < 8; ++kc8) {
            const int k0 = kc8 * 32;
            __syncthreads();   // also covers hw_s read before first E overwrite
            {   // stage E[32][256]: thread = (te = tid&255, half = tid>>8)
                const int te = tid & 255, half = tid >> 8;
                const float* src = enc_states + ((size_t)b * TT + te0 + te) * HD + k0 + half * 16;
                #pragma unroll
                for (int j = 0; j < 4; ++j) {
                    float4 v = ((const float4*)src)[j];
                    E[(half * 16 + j * 4 + 0) * 256 + te] = v.x;
                    E[(half * 16 + j * 4 + 1) * 256 + te] = v.y;
                    E[(half * 16 + j * 4 + 2) * 256 + te] = v.z;
                    E[(half * 16 + j * 4 + 3) * 256 + te] = v.w;
                }
            }
            __syncthreads();
            #pragma unroll 8
            for (int k = 0; k < 32; ++k) {
                const float2 hx2 = *(const float2*)(&Hx[(k0 + k) * 36 + tdt * 2]);
                #pragma unroll
                for (int i = 0; i < 8; ++i) {
                    const float e = E[k * 256 + tet + 32 * i];
                    S[0][i] = fmaf(hx2.x, e, S[0][i]);
                    S[1][i] = fmaf(hx2.y, e, S[1][i]);
                }
            }
        }
        float ewv[8];
        #pragma unroll
        for (int i = 0; i < 8; ++i) {
            const float4 e4 = ((const float4*)qew)[(size_t)b * TT + te0 + tet + 32 * i];
            ewv[i] = (e4.x + e4.y) + (e4.z + e4.w);
        }
        #pragma unroll
        for (int r = 0; r < 2; ++r) {
            float cm = S[r][0];
            #pragma unroll
            for (int i = 1; i < 8; ++i) cm = fmaxf(cm, S[r][i]);
            #pragma unroll
            for (int m = 1; m < 32; m <<= 1) cm = fmaxf(cm, __shfl_xor(cm, m));
            const float newM  = fmaxf(M[r], cm);
            const float scale = __expf(M[r] - newM);
            float nl = 0.f, dl = 0.f;
            #pragma unroll
            for (int i = 0; i < 8; ++i) {
                const float p = __expf(S[r][i] - newM);
                dl += p;
                nl = fmaf(p, ewv[i], nl);
            }
            #pragma unroll
            for (int m = 1; m < 32; m <<= 1) {
                nl += __shfl_xor(nl, m);
                dl += __shfl_xor(dl, m);
            }
            Nm[r] = Nm[r] * scale + nl;
            Dn[r] = Dn[r] * scale + dl;
            M[r]  = newM;
        }
    }

    if (tet == 0) {
        const float lb = lin_b[0];
        #pragma unroll
        for (int r = 0; r < 2; ++r) {
            const int row = tdt * 2 + r;
            out[(size_t)b * TT + td0 + row] = Nm[r] / Dn[r] + hw_s[row] + lb;
        }
    }
}

extern "C" void kernel_launch(void* const* d_in, const int* in_sizes, int n_in,
                              void* d_out, int out_size, void* d_ws, size_t ws_size,
                              hipStream_t stream)
{
    const float* x    = (const float*)d_in[0];
    const float* eWih = (const float*)d_in[1];
    const float* eWhh = (const float*)d_in[2];
    const float* ebih = (const float*)d_in[3];
    const float* ebhh = (const float*)d_in[4];
    const float* dWih = (const float*)d_in[5];
    const float* dWhh = (const float*)d_in[6];
    const float* dbih = (const float*)d_in[7];
    const float* dbhh = (const float*)d_in[8];
    const float* linW = (const float*)d_in[9];
    const float* linb = (const float*)d_in[10];
    float* out = (float*)d_out;

    float* p = (float*)d_ws;
    float* WTe = p;        p += (size_t)GD * HD;
    float* WTd = p;        p += (size_t)GD * HD;
    float* be  = p;        p += GD;
    float* bd  = p;        p += GD;
    float* enc_states = p; p += (size_t)BB * TT * HD;
    float* dec_hs = p;     p += (size_t)BB * TT * HD;
    float* qew = p;        p += (size_t)BB * TT * 4;
    unsigned long long* ex = (unsigned long long*)p; p += (size_t)BB * 2 * 256 * 2;
    unsigned* prog4 = (unsigned*)p; p += 256;

    prep_kernel<<<(GD * HD + 255) / 256, 256, 0, stream>>>(
        eWhh, ebih, ebhh, dWhh, dbih, dbhh, WTe, WTd, be, bd, ex, prog4);

    // encoder (256 blocks co-resident by capacity; folds qew)
    enc_kernel<<<256, NT, 0, stream>>>(
        x, eWih, be, WTe, enc_states, ex, linW, qew);

    // fused decoder + gated attention (dec blocks 0..255 dispatch first)
    tail_kernel<<<256 + BB * (TT / 32), NT, 0, stream>>>(
        x, dWih, bd, WTd, enc_states, dec_hs, ex, prog4,
        qew, linW + HD, linb, out);
}

// Round 9
// 3996.641 us; speedup vs baseline: 10.5582x; 1.0849x over previous
//
// Encoder-decoder LSTM + dot attention + linear, MI355X fp32.  R13
// R12 post-mortem: fusion passed, VGPR 88 ok, visibility protocol validated,
// BUT tail 2717 vs dec-alone 1622: (a) Hx staging was a 16-way LDS bank
// conflict (7.9M cycles) stalling the CU-shared LDS pipe; (b) dec dropped to
// prio0 during poll/publish, letting attn crowd exactly the RTT-critical
// phase; (c) 2GB attn E-traffic. R13 fusion v2:
//  - dec setprio(1) for the WHOLE loop (poll is ~99% waitcnt stall anyway)
//  - Hx stored TRANSPOSED [td][k] pad 260: staging writes lane-consecutive-k
//    (conflict-free), compute reads wave-uniform broadcast
//  - 64-row attn tiles (1024 blocks, 1GB traffic); dec folds qhw quarter-dots
//    (sc0sc1, validated protocol) so attn does zero hw work
// Pred: tail VGPR 88-110, conflicts <1M, tail 1650-2000us, enc ~1620,
// total ~3450-3650. Fail sig: tail >=2500 -> fusion dead, revert serial.
#include <hip/hip_runtime.h>
#include <math.h>

#define HD 256
#define GD 1024   // 4*H
#define TT 1024
#define BB 64
#define NT 512    // block size

typedef float __attribute__((ext_vector_type(4))) f32x4;

__device__ __forceinline__ float sig_(float x)  { return 1.f / (1.f + __expf(-x)); }
__device__ __forceinline__ float tanh_(float x) { return 1.f - 2.f / (1.f + __expf(2.f * x)); }

// ---------------- prep: transpose Whh -> [k][j], bias sums, zero ex + flags ----------
__global__ __launch_bounds__(256) void prep_kernel(
    const float* __restrict__ eW, const float* __restrict__ eb1, const float* __restrict__ eb2,
    const float* __restrict__ dW, const float* __restrict__ db1, const float* __restrict__ db2,
    float* __restrict__ WTe, float* __restrict__ WTd,
    float* __restrict__ be, float* __restrict__ bd,
    unsigned long long* __restrict__ ex,   // [B][2][256] tagged slots
    unsigned* __restrict__ prog4)          // [B][4] progress flags
{
    int idx = blockIdx.x * 256 + threadIdx.x;
    if (idx < GD * HD) {
        int j = idx / HD, k = idx % HD;      // Whh[j][k]
        WTe[k * GD + j] = eW[idx];
        WTd[k * GD + j] = dW[idx];
    }
    if (idx < GD) {
        be[idx] = eb1[idx] + eb2[idx];
        bd[idx] = db1[idx] + db2[idx];
    }
    if (idx < BB * 2 * 256) ex[idx] = 0ULL;   // tags=0 (< any expected tag)
    if (idx < BB * 4) prog4[idx] = 0u;
}

// ---------------- LSTM scan body: EXACT R4 structure ----------------
// block (b,q): q owns dims [64q,64q+64). thread: s=tid&3 (k-quarter), jj=tid>>2.
// qdot fold (lw!=null): quarter-dot of h with lw; wt=1 -> sc0sc1 store (in-kernel
// cross-XCD consumers). prog4!=null -> progress flags every 32 steps.
__device__ __forceinline__ void scan_body(
    const float* __restrict__ x, const float* __restrict__ Wih,
    const float* __restrict__ bias, const float* __restrict__ WT,
    const float* __restrict__ h_init, float* __restrict__ states,
    unsigned long long* __restrict__ ex, unsigned tag0,
    const float* __restrict__ lw, float* __restrict__ qdot, int wt,
    unsigned* __restrict__ prog4,
    float* x_s, float* h_rep /*4*264*/, float* act_s /*256*/,
    int b, int q)
{
    const int tid = threadIdx.x;
    const int s   = tid & 3;
    const int jj  = tid >> 2;
    const int gate = jj >> 5;
    const int kk0  = (jj & 31) * 2;
    const int r0   = gate * 64 + kk0;
    const int jg0  = gate * 256 + q * 64 + kk0;

    float4 w0[16], w1[16];
    {
        const float* basek = WT + (size_t)(s * 64) * GD;
        #pragma unroll
        for (int i = 0; i < 16; ++i) {
            const float* p0 = basek + (size_t)(4 * i) * GD + jg0;
            w0[i] = make_float4(p0[0], p0[GD], p0[2 * GD], p0[3 * GD]);
            const float* p1 = p0 + 1;
            w1[i] = make_float4(p1[0], p1[GD], p1[2 * GD], p1[3 * GD]);
        }
    }
    const float wih0 = Wih[jg0], wih1 = Wih[jg0 + 1];
    const float bj0  = bias[jg0], bj1  = bias[jg0 + 1];
    const float lwd  = lw ? lw[tid & 255] : 0.f;

    for (int i = tid; i < TT; i += NT) x_s[i] = x[b * TT + i];
    if (tid < 256) {
        float hv = h_init ? h_init[((size_t)b * TT + (TT - 1)) * HD + tid] : 0.f;
        h_rep[(tid >> 6) * 264 + (tid & 63)] = hv;
    }
    float c = 0.f;
    __syncthreads();

    __builtin_amdgcn_s_setprio(1);   // protect the scan from co-resident attn waves
    #pragma unroll 1
    for (int t = 0; t < TT; ++t) {
        const float xt = x_s[t];
        float a0p, a1p, a0q = 0.f, a1q = 0.f;
        if (s == 0) { a0p = fmaf(xt, wih0, bj0); a1p = fmaf(xt, wih1, bj1); }
        else        { a0p = 0.f;                 a1p = 0.f; }
        const float4* h4 = (const float4*)(h_rep + s * 264);
        #pragma unroll
        for (int i = 0; i < 8; ++i) {
            float4 hv = h4[i];
            a0p = fmaf(hv.x, w0[i].x, a0p); a0p = fmaf(hv.y, w0[i].y, a0p);
            a0p = fmaf(hv.z, w0[i].z, a0p); a0p = fmaf(hv.w, w0[i].w, a0p);
            a1p = fmaf(hv.x, w1[i].x, a1p); a1p = fmaf(hv.y, w1[i].y, a1p);
            a1p = fmaf(hv.z, w1[i].z, a1p); a1p = fmaf(hv.w, w1[i].w, a1p);
        }
        #pragma unroll
        for (int i = 8; i < 16; ++i) {
            float4 hv = h4[i];
            a0q = fmaf(hv.x, w0[i].x, a0q); a0q = fmaf(hv.y, w0[i].y, a0q);
            a0q = fmaf(hv.z, w0[i].z, a0q); a0q = fmaf(hv.w, w0[i].w, a0q);
            a1q = fmaf(hv.x, w1[i].x, a1q); a1q = fmaf(hv.y, w1[i].y, a1q);
            a1q = fmaf(hv.z, w1[i].z, a1q); a1q = fmaf(hv.w, w1[i].w, a1q);
        }
        float a0 = a0p + a0q;
        float a1 = a1p + a1q;
        a0 += __shfl_xor(a0, 1); a0 += __shfl_xor(a0, 2);
        a1 += __shfl_xor(a1, 1); a1 += __shfl_xor(a1, 2);
        if (s == 0) {
            float2 av;
            av.x = (gate == 2) ? tanh_(a0) : sig_(a0);
            av.y = (gate == 2) ? tanh_(a1) : sig_(a1);
            *(float2*)(&act_s[r0]) = av;
        }
        __syncthreads();   // act ready

        const unsigned tag = tag0 + (unsigned)t + 1u;
        unsigned long long* ssl = ex + ((size_t)b * 2 + (t & 1)) * 256;
        if (tid < 256) {
            const int dq = tid >> 6, dk = tid & 63;   // wave-uniform dq
            if (dq == q) {
                float gi = act_s[dk], gf = act_s[64 + dk], gg = act_s[128 + dk], go = act_s[192 + dk];
                c = fmaf(gf, c, gi * gg);
                float h = go * tanh_(c);
                unsigned long long pk = ((unsigned long long)tag << 32)
                                      | (unsigned long long)__float_as_uint(h);
                // publish FIRST (earliest remote visibility)
                __hip_atomic_store(&ssl[tid], pk, __ATOMIC_RELAXED, __HIP_MEMORY_SCOPE_AGENT);
                h_rep[q * 264 + dk] = h;
                // states write-through to coherence point (attn reads it in-kernel)
                float* sp = &states[((size_t)(b * TT + t)) * HD + tid];
                asm volatile("global_store_dword %0, %1, off sc0 sc1"
                             :: "v"(sp), "v"(h) : "memory");
                if (lw) {   // folded quarter-dot, off critical path (after publish)
                    float v = h * lwd;
                    #pragma unroll
                    for (int m = 1; m < 64; m <<= 1) v += __shfl_xor(v, m);
                    if (dk == 0) {
                        float* qp = &qdot[((size_t)(b * TT + t)) * 4 + q];
                        if (wt) {
                            asm volatile("global_store_dword %0, %1, off sc0 sc1"
                                         :: "v"(qp), "v"(v) : "memory");
                        } else {
                            *qp = v;
                        }
                    }
                }
            } else {
                unsigned long long u;
                const unsigned long long* sp = ssl + tid;
                do {
                    u = __hip_atomic_load(sp, __ATOMIC_RELAXED, __HIP_MEMORY_SCOPE_AGENT);
                } while ((unsigned)(u >> 32) != tag);
                h_rep[dq * 264 + dk] = __uint_as_float((unsigned)u);
            }
        }
        __syncthreads();   // h replicas ready; ALL waves' sc1 stores drained
        // progress flag: relaxed agent store AFTER the barrier drain is sound
        if (prog4 && ((t & 31) == 31) && tid == 0)
            __hip_atomic_store(&prog4[b * 4 + q], (unsigned)((t + 1) >> 5),
                               __ATOMIC_RELAXED, __HIP_MEMORY_SCOPE_AGENT);
    }
    __builtin_amdgcn_s_setprio(0);
}

// ---------------- encoder: standalone scan (+ qew fold, plain store) ----------------
__global__ __launch_bounds__(NT, 2) void enc_kernel(
    const float* __restrict__ x, const float* __restrict__ Wih,
    const float* __restrict__ bias, const float* __restrict__ WT,
    float* __restrict__ states, unsigned long long* __restrict__ ex,
    const float* __restrict__ lw, float* __restrict__ qew)
{
    __shared__ float x_s[TT];
    __shared__ float h_rep[4 * 264];
    __shared__ float act_s[256];
    const int b = (int)blockIdx.x & 63;
    const int q = (int)blockIdx.x >> 6;
    scan_body(x, Wih, bias, WT, nullptr, states, ex, 0u, lw, qew, 0, nullptr,
              x_s, h_rep, act_s, b, q);
}

// ---------------- fused tail: dec scan (blocks 0..255) + gated attn (256..1279) ----
// union LDS: attn Hx_t[64][260] 16640 + E[8][256] 2048 + hw_s 64 = 18752 f
// = 75008B -> 2 blocks/CU by LDS; dec path uses first 2336 f.
#define SMEMF 18752
#define TDA   64     // attn td rows per block
__global__ __launch_bounds__(NT, 2) void tail_kernel(
    const float* __restrict__ x, const float* __restrict__ Wih,
    const float* __restrict__ bias, const float* __restrict__ WT,
    const float* __restrict__ enc_states, float* __restrict__ dec_hs,
    unsigned long long* __restrict__ ex,
    unsigned* __restrict__ prog4,
    const float* __restrict__ qew, float* __restrict__ qhw,
    const float* __restrict__ lw2,
    const float* __restrict__ lin_b, float* __restrict__ out)
{
    __shared__ __align__(16) float smem[SMEMF];
    const int blk = (int)blockIdx.x;
    const int tid = threadIdx.x;

    if (blk < 256) {
        // ---------------- decoder scan (R4 structure + qhw fold) ----------------
        float* x_s   = smem;
        float* h_rep = smem + 1024;
        float* act_s = smem + 1024 + 4 * 264;
        scan_body(x, Wih, bias, WT, enc_states, dec_hs, ex, 1024u,
                  lw2, qhw, 1, prog4, x_s, h_rep, act_s, blk & 63, blk >> 6);
        return;
    }

    // ---------------- attention tile: 64 rows, 512 threads ----------------
    const int ai   = blk - 256;
    const int b    = ai & 63;
    const int tile = ai >> 6;          // 0..15 (low tiles dispatch first)
    const int td0  = tile * TDA;
    float* Hx   = smem;                // Hx_t[64 td][260] (k fast, conflict-free)
    float* E    = smem + 64 * 260;     // [8][256]
    float* hw_s = E + 2048;            // [64]

    // gate: dec rows [td0, td0+64) + qhw ready when min_q prog4[b][q] >= 2(tile+1)
    if (tid == 0) {
        const unsigned need = (unsigned)(tile * 2 + 2);
        for (;;) {
            unsigned m0 = __hip_atomic_load(&prog4[b*4+0], __ATOMIC_RELAXED, __HIP_MEMORY_SCOPE_AGENT);
            unsigned m1 = __hip_atomic_load(&prog4[b*4+1], __ATOMIC_RELAXED, __HIP_MEMORY_SCOPE_AGENT);
            unsigned m2 = __hip_atomic_load(&prog4[b*4+2], __ATOMIC_RELAXED, __HIP_MEMORY_SCOPE_AGENT);
            unsigned m3 = __hip_atomic_load(&prog4[b*4+3], __ATOMIC_RELAXED, __HIP_MEMORY_SCOPE_AGENT);
            unsigned mn = min(min(m0, m1), min(m2, m3));
            if (mn >= need) break;
            __builtin_amdgcn_s_sleep(8);
        }
        (void)__hip_atomic_load(&prog4[b*4], __ATOMIC_ACQUIRE, __HIP_MEMORY_SCOPE_AGENT);
    }
    __syncthreads();

    // stage Hx_t[td][k]: thread = (k = tid&255, tdg = tid>>8); writes are
    // lane-consecutive-k -> conflict-free. Loads sc0sc1 (bypass to coherence pt).
    {
        const int k   = tid & 255;
        const int tdg = tid >> 8;
        #pragma unroll 1
        for (int j0 = 0; j0 < 32; j0 += 4) {
            const int tdb = tdg * 32 + j0;
            const float* s0 = dec_hs + ((size_t)b * TT + td0 + tdb) * HD + k;
            const float* s1 = s0 + HD;
            const float* s2 = s0 + 2 * HD;
            const float* s3 = s0 + 3 * HD;
            float v0, v1, v2, v3;
            asm volatile(
                "global_load_dword %0, %4, off sc0 sc1\n\t"
                "global_load_dword %1, %5, off sc0 sc1\n\t"
                "global_load_dword %2, %6, off sc0 sc1\n\t"
                "global_load_dword %3, %7, off sc0 sc1\n\t"
                "s_waitcnt vmcnt(0)"
                : "=&v"(v0), "=&v"(v1), "=&v"(v2), "=&v"(v3)
                : "v"(s0), "v"(s1), "v"(s2), "v"(s3) : "memory");
            Hx[(tdb + 0) * 260 + k] = v0;
            Hx[(tdb + 1) * 260 + k] = v1;
            Hx[(tdb + 2) * 260 + k] = v2;
            Hx[(tdb + 3) * 260 + k] = v3;
        }
    }
    // hw from dec's folded quarter-dots (sc0sc1 bypass read)
    if (tid < TDA) {
        const float* qp = qhw + ((size_t)b * TT + td0 + tid) * 4;
        f32x4 q4;
        asm volatile("global_load_dwordx4 %0, %1, off sc0 sc1\n\ts_waitcnt vmcnt(0)"
                     : "=&v"(q4) : "v"(qp) : "memory");
        hw_s[tid] = (q4.x + q4.y) + (q4.z + q4.w);
    }

    const int tdt = tid >> 5;   // 0..15 (4 td rows each)
    const int tet = tid & 31;

    float M[4]  = {-1e30f, -1e30f, -1e30f, -1e30f};
    float Nm[4] = {0.f, 0.f, 0.f, 0.f};
    float Dn[4] = {0.f, 0.f, 0.f, 0.f};

    for (int tc = 0; tc < 4; ++tc) {
        const int te0 = tc * 256;
        float S[4][8] = {{0.f}};
        for (int kc = 0; kc < 32; ++kc) {
            const int k0 = kc * 8;
            __syncthreads();   // first iter also covers Hx/hw_s staging
            {   // stage E[8][256]: thread = (te = tid&255, kg = tid>>8 -> 4 k)
                const int te = tid & 255, kg = tid >> 8;
                const float* src = enc_states + ((size_t)b * TT + te0 + te) * HD + k0 + kg * 4;
                float4 v = *(const float4*)src;   // plain: enc_states from prior kernel
                E[(kg * 4 + 0) * 256 + te] = v.x;
                E[(kg * 4 + 1) * 256 + te] = v.y;
                E[(kg * 4 + 2) * 256 + te] = v.z;
                E[(kg * 4 + 3) * 256 + te] = v.w;
            }
            __syncthreads();
            #pragma unroll
            for (int k = 0; k < 8; ++k) {
                const int kk = k0 + k;
                const float hx0 = Hx[(tdt * 4 + 0) * 260 + kk];   // broadcast reads
                const float hx1 = Hx[(tdt * 4 + 1) * 260 + kk];
                const float hx2 = Hx[(tdt * 4 + 2) * 260 + kk];
                const float hx3 = Hx[(tdt * 4 + 3) * 260 + kk];
                #pragma unroll
                for (int i = 0; i < 8; ++i) {
                    const float e = E[k * 256 + tet + 32 * i];
                    S[0][i] = fmaf(hx0, e, S[0][i]);
                    S[1][i] = fmaf(hx1, e, S[1][i]);
                    S[2][i] = fmaf(hx2, e, S[2][i]);
                    S[3][i] = fmaf(hx3, e, S[3][i]);
                }
            }
        }
        float ewv[8];
        #pragma unroll
        for (int i = 0; i < 8; ++i) {
            const float4 e4 = ((const float4*)qew)[(size_t)b * TT + te0 + tet + 32 * i];
            ewv[i] = (e4.x + e4.y) + (e4.z + e4.w);
        }
        #pragma unroll
        for (int r = 0; r < 4; ++r) {
            float cm = S[r][0];
            #pragma unroll
            for (int i = 1; i < 8; ++i) cm = fmaxf(cm, S[r][i]);
            #pragma unroll
            for (int m = 1; m < 32; m <<= 1) cm = fmaxf(cm, __shfl_xor(cm, m));
            const float newM  = fmaxf(M[r], cm);
            const float scale = __expf(M[r] - newM);
            float nl = 0.f, dl = 0.f;
            #pragma unroll
            for (int i = 0; i < 8; ++i) {
                const float p = __expf(S[r][i] - newM);
                dl += p;
                nl = fmaf(p, ewv[i], nl);
            }
            #pragma unroll
            for (int m = 1; m < 32; m <<= 1) {
                nl += __shfl_xor(nl, m);
                dl += __shfl_xor(dl, m);
            }
            Nm[r] = Nm[r] * scale + nl;
            Dn[r] = Dn[r] * scale + dl;
            M[r]  = newM;
        }
    }

    if (tet == 0) {
        const float lb = lin_b[0];
        #pragma unroll
        for (int r = 0; r < 4; ++r) {
            const int row = tdt * 4 + r;
            out[(size_t)b * TT + td0 + row] = Nm[r] / Dn[r] + hw_s[row] + lb;
        }
    }
}

extern "C" void kernel_launch(void* const* d_in, const int* in_sizes, int n_in,
                              void* d_out, int out_size, void* d_ws, size_t ws_size,
                              hipStream_t stream)
{
    const float* x    = (const float*)d_in[0];
    const float* eWih = (const float*)d_in[1];
    const float* eWhh = (const float*)d_in[2];
    const float* ebih = (const float*)d_in[3];
    const float* ebhh = (const float*)d_in[4];
    const float* dWih = (const float*)d_in[5];
    const float* dWhh = (const float*)d_in[6];
    const float* dbih = (const float*)d_in[7];
    const float* dbhh = (const float*)d_in[8];
    const float* linW = (const float*)d_in[9];
    const float* linb = (const float*)d_in[10];
    float* out = (float*)d_out;

    float* p = (float*)d_ws;
    float* WTe = p;        p += (size_t)GD * HD;
    float* WTd = p;        p += (size_t)GD * HD;
    float* be  = p;        p += GD;
    float* bd  = p;        p += GD;
    float* enc_states = p; p += (size_t)BB * TT * HD;
    float* dec_hs = p;     p += (size_t)BB * TT * HD;
    float* qew = p;        p += (size_t)BB * TT * 4;
    float* qhw = p;        p += (size_t)BB * TT * 4;
    unsigned long long* ex = (unsigned long long*)p; p += (size_t)BB * 2 * 256 * 2;
    unsigned* prog4 = (unsigned*)p; p += 256;

    prep_kernel<<<(GD * HD + 255) / 256, 256, 0, stream>>>(
        eWhh, ebih, ebhh, dWhh, dbih, dbhh, WTe, WTd, be, bd, ex, prog4);

    // encoder (256 blocks co-resident by capacity; folds qew, plain stores)
    enc_kernel<<<256, NT, 0, stream>>>(
        x, eWih, be, WTe, enc_states, ex, linW, qew);

    // fused decoder + gated attention (dec blocks 0..255 dispatch first)
    tail_kernel<<<256 + BB * (TT / TDA), NT, 0, stream>>>(
        x, dWih, bd, WTd, enc_states, dec_hs, ex, prog4,
        qew, qhw, linW + HD, linb, out);
}